// Round 2
// baseline (637.890 us; speedup 1.0000x reference)
//
#include <hip/hip_runtime.h>

// GeodesicShooting on [160^3,3] f32:
//   1) separable Gaussian blur (k=9, zero-pad), scaled by 2^-6
//   2) 6x scaling-and-squaring: v <- v + trilinear_sample(v, id + v)
// Internal layout: SoA ([3][D][H][W]) for coalescing; final step writes AoS.
// Identity grid is computed analytically: sample_x = x + 79.5 * vx.

constexpr int W = 160, H = 160, D = 160;
constexpr int NVOX = W * H * D;            // 4,096,000
constexpr int NSTEPS = 6;
constexpr float HSC = 79.5f;               // 0.5 * (W-1), cubic volume

__device__ __forceinline__ int iclamp(int v, int lo, int hi) {
    return v < lo ? lo : (v > hi ? hi : v);
}

// ---- blur along D axis: AoS input (velocity) -> SoA output ----
__global__ void blur_d_aos2soa(const float* __restrict__ in, float* __restrict__ out,
                               const float* __restrict__ kern, int klen)
{
    int i = blockIdx.x * blockDim.x + threadIdx.x;
    if (i >= NVOX) return;
    int z = i / (W * H);
    int R = (klen - 1) / 2;
    float a0 = 0.f, a1 = 0.f, a2 = 0.f;
    for (int t = 0; t < klen; ++t) {
        int zz = z + t - R;
        if (zz < 0 || zz >= D) continue;               // zero padding
        const float* p = in + (size_t)(i + (t - R) * W * H) * 3;
        float w = kern[t];
        a0 = fmaf(w, p[0], a0);
        a1 = fmaf(w, p[1], a1);
        a2 = fmaf(w, p[2], a2);
    }
    out[i]            = a0;
    out[i + NVOX]     = a1;
    out[i + 2 * NVOX] = a2;
}

// ---- blur along one axis, SoA -> SoA ----
// axis coord = (i / div) % len ; neighbor step = strideVox
__global__ void blur_soa(const float* __restrict__ in, float* __restrict__ out,
                         const float* __restrict__ kern, int klen,
                         int len, int div, int strideVox, float scale)
{
    int i = blockIdx.x * blockDim.x + threadIdx.x;
    if (i >= NVOX) return;
    int c = (i / div) % len;
    int R = (klen - 1) / 2;
    float acc[3] = {0.f, 0.f, 0.f};
#pragma unroll
    for (int comp = 0; comp < 3; ++comp) {
        const float* p = in + (size_t)comp * NVOX + i;
        float a = 0.f;
        for (int t = 0; t < klen; ++t) {
            int cc = c + t - R;
            if (cc < 0 || cc >= len) continue;
            a = fmaf(kern[t], p[(t - R) * strideVox], a);
        }
        acc[comp] = a * scale;
    }
    out[i]            = acc[0];
    out[i + NVOX]     = acc[1];
    out[i + 2 * NVOX] = acc[2];
}

// ---- one scaling-and-squaring step, SoA input ----
// AOS_OUT=false: SoA output (intermediate). AOS_OUT=true: AoS output (final, d_out).
template<bool AOS_OUT>
__global__ void step_soa(const float* __restrict__ v, float* __restrict__ out)
{
    int i = blockIdx.x * blockDim.x + threadIdx.x;
    if (i >= NVOX) return;
    int x = i % W;
    int t = i / W;
    int y = t % H;
    int z = t / H;

    float vx = v[i];
    float vy = v[i + NVOX];
    float vz = v[i + 2 * NVOX];

    // identity grid folded in analytically: s = idx + 79.5 * v
    float sx = fmaf(vx, HSC, (float)x);
    float sy = fmaf(vy, HSC, (float)y);
    float sz = fmaf(vz, HSC, (float)z);

    float fx = floorf(sx), fy = floorf(sy), fz = floorf(sz);
    int x0 = (int)fx, y0 = (int)fy, z0 = (int)fz;
    float wx1 = sx - fx, wy1 = sy - fy, wz1 = sz - fz;
    float wx0 = 1.f - wx1, wy0 = 1.f - wy1, wz0 = 1.f - wz1;

    // per-axis validity masks (zeros padding), folded into 1D weights
    wx0 *= (x0     >= 0 && x0     < W) ? 1.f : 0.f;
    wx1 *= (x0 + 1 >= 0 && x0 + 1 < W) ? 1.f : 0.f;
    wy0 *= (y0     >= 0 && y0     < H) ? 1.f : 0.f;
    wy1 *= (y0 + 1 >= 0 && y0 + 1 < H) ? 1.f : 0.f;
    wz0 *= (z0     >= 0 && z0     < D) ? 1.f : 0.f;
    wz1 *= (z0 + 1 >= 0 && z0 + 1 < D) ? 1.f : 0.f;

    // clamped indices keep all loads in-bounds; masked weights give correctness
    int xc0 = iclamp(x0, 0, W - 1), xc1 = iclamp(x0 + 1, 0, W - 1);
    int yc0 = iclamp(y0, 0, H - 1), yc1 = iclamp(y0 + 1, 0, H - 1);
    int zc0 = iclamp(z0, 0, D - 1), zc1 = iclamp(z0 + 1, 0, D - 1);

    int r00 = (zc0 * H + yc0) * W;
    int r01 = (zc0 * H + yc1) * W;
    int r10 = (zc1 * H + yc0) * W;
    int r11 = (zc1 * H + yc1) * W;

    float w00 = wz0 * wy0, w01 = wz0 * wy1, w10 = wz1 * wy0, w11 = wz1 * wy1;

    float res[3];
#pragma unroll
    for (int comp = 0; comp < 3; ++comp) {
        const float* p = v + (size_t)comp * NVOX;
        float s =
            w00 * (wx0 * p[r00 + xc0] + wx1 * p[r00 + xc1]) +
            w01 * (wx0 * p[r01 + xc0] + wx1 * p[r01 + xc1]) +
            w10 * (wx0 * p[r10 + xc0] + wx1 * p[r10 + xc1]) +
            w11 * (wx0 * p[r11 + xc0] + wx1 * p[r11 + xc1]);
        res[comp] = s;
    }

    if (AOS_OUT) {
        float* q = out + (size_t)i * 3;
        q[0] = vx + res[0];
        q[1] = vy + res[1];
        q[2] = vz + res[2];
    } else {
        out[i]            = vx + res[0];
        out[i + NVOX]     = vy + res[1];
        out[i + 2 * NVOX] = vz + res[2];
    }
}

extern "C" void kernel_launch(void* const* d_in, const int* in_sizes, int n_in,
                              void* d_out, int out_size, void* d_ws, size_t ws_size,
                              hipStream_t stream)
{
    const float* vel = (const float*)d_in[0];
    // d_in[1] (grid) unused: identity grid computed analytically
    const float* gk  = (const float*)d_in[2];
    int klen = in_sizes[2];                  // 9

    float* OUT = (float*)d_out;              // doubles as SoA scratch until final write
    float* WS  = (float*)d_ws;               // one [3][D][H][W] f32 buffer (49.2 MB)

    const int threads = 256;
    const int blocks = (NVOX + threads - 1) / threads;
    const float scale = 1.0f / (float)(1 << NSTEPS);   // 2^-6

    // blur: D axis (AoS->SoA), H axis, W axis (scale fused)
    blur_d_aos2soa<<<blocks, threads, 0, stream>>>(vel, OUT, gk, klen);
    blur_soa<<<blocks, threads, 0, stream>>>(OUT, WS, gk, klen, H, W, W, 1.0f);
    blur_soa<<<blocks, threads, 0, stream>>>(WS, OUT, gk, klen, W, 1, 1, scale);

    // 6 squaring steps: OUT -> WS -> OUT -> WS -> OUT -> WS -> OUT(AoS)
    step_soa<false><<<blocks, threads, 0, stream>>>(OUT, WS);
    step_soa<false><<<blocks, threads, 0, stream>>>(WS, OUT);
    step_soa<false><<<blocks, threads, 0, stream>>>(OUT, WS);
    step_soa<false><<<blocks, threads, 0, stream>>>(WS, OUT);
    step_soa<false><<<blocks, threads, 0, stream>>>(OUT, WS);
    step_soa<true ><<<blocks, threads, 0, stream>>>(WS, OUT);   // final: AoS into d_out
}